// Round 14
// baseline (88.676 us; speedup 1.0000x reference)
//
#include <hip/hip_runtime.h>
#include <hip/hip_bf16.h>
#include <float.h>

#define BB   32
#define PP   16384
#define NOBJ 50
#define NCLS 21
#define PBLK 64    // blocks of 256 priors per image in k_main (P/256)
#define NBLK (BB * PBLK)
#define OGRP 13    // object groups of 4 (covers 50..51 with clamp)

// ---------------- workspace layout ----------------
// [0]        u64    bp_part[2][BB*64]      (32 KB)  per-half best-prior keys
// [262144]   double pc_conf[NBLK]          (16 KB)
// [278528]   double pc_loc[NBLK]           (16 KB)
// [294912]   int    pc_npos[NBLK]          (8 KB)
// [303104]   double hard[BB]               (256 B)
// [327680]   u64    perprior[BB*PP]        (4 MB)   FINAL per-prior keys
// [33554432] float  neg[BB*PP]             (2 MB)

// per-prior argmax over ALL 50 objects: 512 priors/block, 2 priors/thread,
// boxes staged in LDS (broadcast b128 reads). Output is FINAL (no partials).
__global__ __launch_bounds__(256) void k_prior(
    const float* __restrict__ boxes, const float* __restrict__ priors,
    unsigned long long* __restrict__ perprior)
{
#pragma clang fp contract(off)
    const int b     = (int)blockIdx.x >> 5;
    const int pbase = ((int)blockIdx.x & 31) << 9;
    const int t     = (int)threadIdx.x;

    __shared__ float4 sbox[NOBJ];
    if (t < NOBJ) sbox[t] = reinterpret_cast<const float4*>(boxes)[b * NOBJ + t];

    float px0[2], py0[2], px1[2], py1[2], pab[2];
#pragma unroll
    for (int j = 0; j < 2; ++j) {
        float4 pc = reinterpret_cast<const float4*>(priors)[pbase + t + j * 256];
        float hx = pc.z * 0.5f, hy = pc.w * 0.5f;
        px0[j] = pc.x - hx; py0[j] = pc.y - hy;
        px1[j] = pc.x + hx; py1[j] = pc.y + hy;
        pab[j] = (px1[j] - px0[j]) * (py1[j] - py0[j]);
    }
    __syncthreads();

    float bf[2] = {-1.0f, -1.0f}; int bn[2] = {0, 0};
#pragma unroll 10
    for (int n = 0; n < NOBJ; ++n) {
        float4 bx = sbox[n];                     // broadcast (conflict-free)
        float aarea = (bx.z - bx.x) * (bx.w - bx.y);
#pragma unroll
        for (int j = 0; j < 2; ++j) {
            float ltx = fmaxf(bx.x, px0[j]), lty = fmaxf(bx.y, py0[j]);
            float rbx = fminf(bx.z, px1[j]), rby = fminf(bx.w, py1[j]);
            float dx = fmaxf(rbx - ltx, 0.0f);
            float dy = fmaxf(rby - lty, 0.0f);
            float inter = dx * dy;
            float iou = __fdividef(inter, (aarea + pab[j]) - inter);
            // ascending n + strict > : first-max = smallest n (argmax axis 0)
            if (iou > bf[j]) { bf[j] = iou; bn[j] = n; }
        }
    }
#pragma unroll
    for (int j = 0; j < 2; ++j) {
        unsigned long long key =
            ((unsigned long long)__float_as_uint(bf[j]) << 32) |
            (unsigned long long)(unsigned)(NOBJ - 1 - bn[j]);
        perprior[(size_t)b * PP + pbase + t + j * 256] = key;
    }
}

// per-object argmax over priors: one WAVE per (object, prior-half).
// Lane streams 128 coalesced float4 priors; register tracker; one shuffle
// reduce; plain store. No LDS, no atomics.
__global__ __launch_bounds__(256) void k_obj(
    const float* __restrict__ boxes, const float* __restrict__ priors,
    unsigned long long* __restrict__ bp_part)
{
#pragma clang fp contract(off)
    const int blk = (int)blockIdx.x;
    const int b   = blk / (OGRP * 2);
    const int rem = blk % (OGRP * 2);
    const int og  = rem >> 1;
    const int h   = rem & 1;
    const int t   = (int)threadIdx.x;
    const int w   = t >> 6, l = t & 63;

    const int n  = og * 4 + w;
    const int nn = n < NOBJ ? n : NOBJ - 1;       // clamp (store skipped)
    float4 bx = reinterpret_cast<const float4*>(boxes)[b * NOBJ + nn];
    float aarea = (bx.z - bx.x) * (bx.w - bx.y);

    const float4* gpri = reinterpret_cast<const float4*>(priors) + h * 8192;
    float bf = -1.0f; int bp = 0;
#pragma unroll 8
    for (int i = 0; i < 128; ++i) {
        float4 pc = gpri[i * 64 + l];             // coalesced, L2-resident
        float hx = pc.z * 0.5f, hy = pc.w * 0.5f;
        float px0 = pc.x - hx, py0 = pc.y - hy;
        float px1 = pc.x + hx, py1 = pc.y + hy;
        float pab = (px1 - px0) * (py1 - py0);
        float ltx = fmaxf(bx.x, px0), lty = fmaxf(bx.y, py0);
        float rbx = fminf(bx.z, px1), rby = fminf(bx.w, py1);
        float dx = fmaxf(rbx - ltx, 0.0f);
        float dy = fmaxf(rby - lty, 0.0f);
        float inter = dx * dy;
        float iou = __fdividef(inter, (aarea + pab) - inter);
        // ascending i (=ascending p per lane) + strict > : smallest p
        if (iou > bf) { bf = iou; bp = h * 8192 + i * 64 + l; }
    }
    unsigned long long v =
        ((unsigned long long)__float_as_uint(bf) << 32) |
        (unsigned long long)(0xFFFFFFFFu - (unsigned)bp);
    for (int o = 32; o > 0; o >>= 1) {
        unsigned long long other = __shfl_down(v, o, 64);
        if (other > v) v = other;                 // key tiebreak: smallest p
    }
    if (l == 0 && n < NOBJ)
        bp_part[(size_t)h * BB * 64 + b * 64 + n] = v;
}

// fused: per-prior key load + forced-prior table + label/L1/CE + partials
__global__ __launch_bounds__(256) void k_main(
    const float* __restrict__ locs, const float* __restrict__ scores,
    const float* __restrict__ boxes, const int* __restrict__ labels,
    const float* __restrict__ priors,
    const unsigned long long* __restrict__ bp_part,
    const unsigned long long* __restrict__ perprior,
    float* __restrict__ neg, double* __restrict__ pc_conf,
    double* __restrict__ pc_loc, int* __restrict__ pc_npos)
{
#pragma clang fp contract(off)
    const int b   = (int)blockIdx.x >> 6;
    const int p0  = ((int)blockIdx.x & 63) << 8;
    const int t   = (int)threadIdx.x;
    const int p   = p0 + t;
    const int idx = b * PP + p;

    __shared__ float  sls[256 * NCLS];
    __shared__ int    sforce[256];           // local prior -> forcing object
    __shared__ float4 sbox[NOBJ];
    __shared__ int    slab[NOBJ];
    __shared__ double sconf[4], sloc[4];
    __shared__ int    snp[4];

    // stage 256x21 scores tile via coalesced float4 loads
    {
        const float4* gsc = reinterpret_cast<const float4*>(
            scores + (size_t)(b * PP + p0) * NCLS);
        float4* dls = reinterpret_cast<float4*>(sls);
#pragma unroll
        for (int i = 0; i < 6; ++i) {
            int j = i * 256 + t;
            if (j < (256 * NCLS) / 4) dls[j] = gsc[j];
        }
    }
    sforce[t] = -1;
    if (t < NOBJ) {
        sbox[t] = reinterpret_cast<const float4*>(boxes)[b * NOBJ + t];
        slab[t] = labels[b * NOBJ + t];
    }
    __syncthreads();
    if (t < NOBJ) {
        unsigned long long k0 = bp_part[b * 64 + t];
        unsigned long long k1 = bp_part[(size_t)BB * 64 + b * 64 + t];
        if (k1 > k0) k0 = k1;
        int spf = (int)(0xFFFFFFFFu - (unsigned)(k0 & 0xFFFFFFFFull));
        if (spf >= p0 && spf < p0 + 256)
            atomicMax(&sforce[spf - p0], t);   // max n = last-wins scatter
    }
    __syncthreads();

    // per-prior argmax: single final key load
    unsigned long long key = perprior[(size_t)b * PP + p];
    int   bestn = NOBJ - 1 - (int)((unsigned)key & 63u);
    float v     = __uint_as_float((unsigned)(key >> 32));
    int fn = sforce[t];
    if (fn >= 0) { bestn = fn; v = 1.0f; }

    int lbl = slab[bestn];
    if (v < 0.5f) lbl = 0;
    const bool pos = (lbl != 0);

    float locl1 = 0.0f;
    if (pos) {
        float4 bx = sbox[bestn];
        float4 pc = reinterpret_cast<const float4*>(priors)[p];
        float cx = (bx.x + bx.z) / 2.0f;
        float cy = (bx.y + bx.w) / 2.0f;
        float w  = bx.z - bx.x, h = bx.w - bx.y;
        float gx = (cx - pc.x) / (pc.z / 10.0f);
        float gy = (cy - pc.y) / (pc.w / 10.0f);
        float gw = logf(w / pc.z) * 5.0f;
        float gh = logf(h / pc.w) * 5.0f;
        float4 pl = reinterpret_cast<const float4*>(locs)[idx];
        locl1 = fabsf(pl.x - gx) + fabsf(pl.y - gy) +
                fabsf(pl.z - gw) + fabsf(pl.w - gh);
    }

    // cross-entropy via log-softmax over 21 classes (from LDS)
    float x[NCLS];
    float m = -FLT_MAX;
#pragma unroll
    for (int c = 0; c < NCLS; ++c) { x[c] = sls[t * NCLS + c]; m = fmaxf(m, x[c]); }
    float tgt = sls[t * NCLS + lbl];
    float s = 0.0f;
#pragma unroll
    for (int c = 0; c < NCLS; ++c) s += expf(x[c] - m);
    float ce = (logf(s) + m) - tgt;

    neg[idx] = pos ? 0.0f : ce;

    // wave reductions -> per-block partials (NO global atomics)
    float cp = pos ? ce : 0.0f;
    unsigned long long bal = __ballot(pos);
    float s1 = cp, s2 = locl1;
    for (int o = 32; o > 0; o >>= 1) {
        s1 += __shfl_down(s1, o, 64);
        s2 += __shfl_down(s2, o, 64);
    }
    if ((t & 63) == 0) {
        int w = t >> 6;
        sconf[w] = (double)s1;
        sloc[w]  = (double)s2;
        snp[w]   = (int)__popcll(bal);
    }
    __syncthreads();
    if (t == 0) {
        pc_conf[blockIdx.x] = sconf[0] + sconf[1] + sconf[2] + sconf[3];
        pc_loc[blockIdx.x]  = sloc[0] + sloc[1] + sloc[2] + sloc[3];
        pc_npos[blockIdx.x] = snp[0] + snp[1] + snp[2] + snp[3];
    }
}

// exact top-K sum via 4x8-bit radix select; values register-resident,
// per-LANE histogram copies, parallel suffix-scan bin selection.
__global__ __launch_bounds__(1024) void k_topk(
    const float* __restrict__ neg, const int* __restrict__ pc_npos,
    double* __restrict__ hard)
{
    const int b    = (int)blockIdx.x;
    const int t    = (int)threadIdx.x;
    const int lane = t & 63;
    const int wid  = t >> 6;

    __shared__ unsigned hist[64 * 257];        // per-lane copies, padded
    __shared__ unsigned ssuf[256];
    __shared__ unsigned s_bb, s_above;
    __shared__ float swave[16];
    __shared__ int s_np;

    if (t < 64) {
        int v = pc_npos[b * PBLK + t];
        for (int o = 32; o > 0; o >>= 1) v += __shfl_down(v, o, 64);
        if (t == 0) s_np = v;
    }

    float v[16];
    {
        const float4* g = reinterpret_cast<const float4*>(neg + (size_t)b * PP);
#pragma unroll
        for (int i = 0; i < 4; ++i) {
            float4 q = g[i * 1024 + t];
            v[i*4+0] = q.x; v[i*4+1] = q.y; v[i*4+2] = q.z; v[i*4+3] = q.w;
        }
    }
    __syncthreads();

    long long K = 3LL * (long long)s_np;
    if (K > PP) K = PP;
    unsigned remaining = (unsigned)K;
    unsigned prefix = 0, mask = 0;
    float mySum = 0.0f;

    for (int shift = 24; shift >= 0; shift -= 8) {
        for (int i = t; i < 64 * 257; i += 1024) hist[i] = 0;
        __syncthreads();
        unsigned* h = hist + lane * 257;
#pragma unroll
        for (int i = 0; i < 16; ++i) {
            unsigned u = __float_as_uint(v[i]);
            if ((u & mask) == prefix) atomicAdd(&h[(u >> shift) & 255u], 1u);
        }
        __syncthreads();
        unsigned cnt = 0;
        if (t < 256) {
#pragma unroll
            for (int w = 0; w < 64; ++w) cnt += hist[w * 257 + t];
            ssuf[t] = cnt;
        }
        __syncthreads();
        for (int off = 1; off < 256; off <<= 1) {
            unsigned add = 0;
            if (t < 256 && t + off < 256) add = ssuf[t + off];
            __syncthreads();
            if (t < 256) ssuf[t] += add;
            __syncthreads();
        }
        if (t < 256) {
            unsigned suf = ssuf[t];
            if (suf >= remaining && suf - cnt < remaining) {
                s_bb = (unsigned)t; s_above = suf - cnt;
            }
        }
        __syncthreads();
        unsigned bb = s_bb;
#pragma unroll
        for (int i = 0; i < 16; ++i) {
            unsigned u = __float_as_uint(v[i]);
            if ((u & mask) == prefix && ((u >> shift) & 255u) > bb)
                mySum += v[i];
        }
        remaining -= s_above;
        prefix |= bb << shift;
        mask   |= 255u << shift;
        __syncthreads();
    }

    float s = mySum;
    for (int o = 32; o > 0; o >>= 1) s += __shfl_down(s, o, 64);
    if ((t & 63) == 0) swave[wid] = s;
    __syncthreads();
    if (t == 0) {
        float tot = 0.0f;
        for (int w = 0; w < 16; ++w) tot += swave[w];
        if (remaining) tot += (float)remaining * __uint_as_float(prefix);
        hard[b] = (double)tot;               // plain store, no atomics
    }
}

__global__ __launch_bounds__(256) void k_final(
    const double* __restrict__ pc_conf, const double* __restrict__ pc_loc,
    const int* __restrict__ pc_npos, const double* __restrict__ hard,
    float* __restrict__ out)
{
    const int t = (int)threadIdx.x;
    __shared__ double sa[4], sb[4], sh[4];
    __shared__ int sn[4];
    double a = 0.0, c = 0.0, h = 0.0; int np = 0;
    for (int i = t; i < NBLK; i += 256) {
        a += pc_conf[i]; c += pc_loc[i]; np += pc_npos[i];
    }
    if (t < BB) h = hard[t];
    for (int o = 32; o > 0; o >>= 1) {
        a += __shfl_down(a, o, 64);
        c += __shfl_down(c, o, 64);
        h += __shfl_down(h, o, 64);
        np += __shfl_down(np, o, 64);
    }
    if ((t & 63) == 0) { int w = t >> 6; sa[w]=a; sb[w]=c; sh[w]=h; sn[w]=np; }
    __syncthreads();
    if (t == 0) {
        double at = sa[0]+sa[1]+sa[2]+sa[3];
        double ct = sb[0]+sb[1]+sb[2]+sb[3];
        double ht = sh[0]+sh[1]+sh[2]+sh[3];
        double npt = (double)(sn[0]+sn[1]+sn[2]+sn[3]);
        out[0] = (float)((at + ht) / npt + ct / (npt * 4.0));
    }
}

extern "C" void kernel_launch(void* const* d_in, const int* in_sizes, int n_in,
                              void* d_out, int out_size, void* d_ws, size_t ws_size,
                              hipStream_t stream) {
    const float* locs   = (const float*)d_in[0];
    const float* scores = (const float*)d_in[1];
    const float* boxes  = (const float*)d_in[2];
    const int*   labels = (const int*)d_in[3];
    const float* priors = (const float*)d_in[4];

    char* ws = (char*)d_ws;
    unsigned long long* bp_part = (unsigned long long*)ws;
    double* pc_conf = (double*)(ws + 262144);
    double* pc_loc  = (double*)(ws + 278528);
    int*    pc_npos = (int*)(ws + 294912);
    double* hard    = (double*)(ws + 303104);
    unsigned long long* perprior = (unsigned long long*)(ws + 327680);
    float*  neg     = (float*)(ws + 33554432);
    float*  out     = (float*)d_out;

    hipLaunchKernelGGL(k_prior, dim3(BB * 32),       dim3(256),  0, stream,
                       boxes, priors, perprior);
    hipLaunchKernelGGL(k_obj,   dim3(BB * OGRP * 2), dim3(256),  0, stream,
                       boxes, priors, bp_part);
    hipLaunchKernelGGL(k_main,  dim3(NBLK),          dim3(256),  0, stream,
                       locs, scores, boxes, labels, priors, bp_part, perprior,
                       neg, pc_conf, pc_loc, pc_npos);
    hipLaunchKernelGGL(k_topk,  dim3(BB),            dim3(1024), 0, stream,
                       neg, pc_npos, hard);
    hipLaunchKernelGGL(k_final, dim3(1),             dim3(256),  0, stream,
                       pc_conf, pc_loc, pc_npos, hard, out);
}

// Round 15
// 68.300 us; speedup vs baseline: 1.2983x; 1.2983x over previous
//
#include <hip/hip_runtime.h>
#include <hip/hip_bf16.h>
#include <float.h>

#define BB   32
#define PP   16384
#define NOBJ 50
#define NCLS 21
#define PBLK 64    // blocks of 256 priors per image in k_main (P/256)
#define NBLK (BB * PBLK)
#define NGRP 7     // object groups of 8 (covers 50 with clamp dups)
#define NCHK 8     // prior chunks of 2048 in k_iou
#define CPRI 2048
#define JPT  8     // priors per thread in k_iou

// ---------------- workspace layout ----------------
// [0]        u64    bp_part[8][BB*NOBJ]    (102400 B) per-chunk best-prior keys
// [262144]   double pc_conf[NBLK]          (16 KB)
// [278528]   double pc_loc[NBLK]           (16 KB)
// [294912]   int    pc_npos[NBLK]          (8 KB)
// [303104]   double hard[BB]               (256 B)
// [327680]   u32    ovp_part[7][BB*PP]     (14.3 MB) per-group best-object keys
// [33554432] float  neg[BB*PP]             (2 MB)

// single IoU-grid pass: 8 objects x 2048 priors per block, 8 priors/thread.
// Per-object reduce via LDS scoreboard. Per-prior partials packed u32:
// ((iou_bits<<2)&~63)|(49-n) — monotone in iou (4 mantissa bits truncated),
// tie -> smaller n; halves the partial-grid traffic vs u64.
__global__ __launch_bounds__(256) void k_iou(
    const float* __restrict__ boxes, const float* __restrict__ priors,
    unsigned long long* __restrict__ bp_part,
    unsigned* __restrict__ ovp_part)
{
#pragma clang fp contract(off)
    const int blk   = (int)blockIdx.x;
    const int b     = blk / (NGRP * NCHK);
    const int rem   = blk % (NGRP * NCHK);
    const int g     = rem / NCHK;
    const int c     = rem % NCHK;
    const int n0    = g * 8;
    const int pbase = c * CPRI;
    const int t     = (int)threadIdx.x;

    __shared__ unsigned long long skey[8][256];   // 16 KB scoreboard

    // 8 boxes in registers (uniform -> s_load)
    float ax0[8], ay0[8], ax1[8], ay1[8], aarea[8];
#pragma unroll
    for (int k = 0; k < 8; ++k) {
        int nn = n0 + k; if (nn >= NOBJ) nn = NOBJ - 1;   // clamp: dup of n=49
        float4 bx = reinterpret_cast<const float4*>(boxes)[b * NOBJ + nn];
        ax0[k] = bx.x; ay0[k] = bx.y; ax1[k] = bx.z; ay1[k] = bx.w;
        aarea[k] = (bx.z - bx.x) * (bx.w - bx.y);
    }

    // 8 priors in registers (coalesced)
    float px0[JPT], py0[JPT], px1[JPT], py1[JPT], pab[JPT];
#pragma unroll
    for (int j = 0; j < JPT; ++j) {
        float4 pc = reinterpret_cast<const float4*>(priors)[pbase + t + j * 256];
        float hx = pc.z * 0.5f, hy = pc.w * 0.5f;   // *0.5 == /2 exactly
        px0[j] = pc.x - hx; py0[j] = pc.y - hy;
        px1[j] = pc.x + hx; py1[j] = pc.y + hy;
        pab[j] = (px1[j] - px0[j]) * (py1[j] - py0[j]);
    }

    float bof[8];  int bop[8];     // best prior per object (this thread)
    float bpf[JPT]; int bpn[JPT];  // best object per prior
#pragma unroll
    for (int k = 0; k < 8; ++k) { bof[k] = -1.0f; bop[k] = 0; }
#pragma unroll
    for (int j = 0; j < JPT; ++j) { bpf[j] = -1.0f; bpn[j] = 0; }

#pragma unroll
    for (int k = 0; k < 8; ++k) {
#pragma unroll
        for (int j = 0; j < JPT; ++j) {
            float ltx = fmaxf(ax0[k], px0[j]), lty = fmaxf(ay0[k], py0[j]);
            float rbx = fminf(ax1[k], px1[j]), rby = fminf(ay1[k], py1[j]);
            float dx = fmaxf(rbx - ltx, 0.0f);
            float dy = fmaxf(rby - lty, 0.0f);
            float inter = dx * dy;
            float iou = __fdividef(inter, (aarea[k] + pab[j]) - inter);
            // ascending j (=ascending p) + strict > : first-max = smallest p
            if (iou > bof[k]) { bof[k] = iou; bop[k] = pbase + t + j * 256; }
            // ascending k (=ascending n) + strict > : first-max = smallest n
            if (iou > bpf[j]) { bpf[j] = iou; bpn[j] = n0 + k; }
        }
    }

    // per-prior partial: packed u32, plain coalesced store
#pragma unroll
    for (int j = 0; j < JPT; ++j) {
        unsigned key32 = ((__float_as_uint(bpf[j]) << 2) & 0xFFFFFFC0u) |
                         (unsigned)(NOBJ - 1 - bpn[j]);
        ovp_part[((size_t)g * BB + b) * PP + pbase + t + j * 256] = key32;
    }

    // per-object: LDS scoreboard tree reduce (key encodes tiebreak -> any order)
#pragma unroll
    for (int k = 0; k < 8; ++k)
        skey[k][t] = ((unsigned long long)__float_as_uint(bof[k]) << 32) |
                     (unsigned long long)(0xFFFFFFFFu - (unsigned)bop[k]);
    __syncthreads();
    {   // stage 1: 8 objects x 32 threads, each folds 8 strided entries
        int k2 = t >> 5, sl = t & 31;
        unsigned long long bestv = skey[k2][sl];
#pragma unroll
        for (int i = 1; i < 8; ++i) {
            unsigned long long cand = skey[k2][sl + 32 * i];
            if (cand > bestv) bestv = cand;
        }
        __syncthreads();
        skey[k2][sl] = bestv;          // compact into cols 0..31
    }
    __syncthreads();
    if (t < 64) {                      // stage 2: 8 objects x 8 threads fold 4
        int k2 = t >> 3, sl = t & 7;
        unsigned long long bestv = skey[k2][sl * 4];
#pragma unroll
        for (int i = 1; i < 4; ++i) {
            unsigned long long cand = skey[k2][sl * 4 + i];
            if (cand > bestv) bestv = cand;
        }
        skey[k2][32 + sl] = bestv;     // park in cols 32..39
    }
    __syncthreads();
    if (t < 8 && n0 + t < NOBJ) {      // stage 3: 8 threads fold 8
        unsigned long long bestv = skey[t][32];
#pragma unroll
        for (int i = 1; i < 8; ++i) {
            unsigned long long cand = skey[t][32 + i];
            if (cand > bestv) bestv = cand;
        }
        bp_part[(size_t)c * BB * NOBJ + b * NOBJ + n0 + t] = bestv;
    }
}

// fused: merge per-prior keys + forced-prior table + label/L1/CE + partials
__global__ __launch_bounds__(256) void k_main(
    const float* __restrict__ locs, const float* __restrict__ scores,
    const float* __restrict__ boxes, const int* __restrict__ labels,
    const float* __restrict__ priors,
    const unsigned long long* __restrict__ bp_part,
    const unsigned* __restrict__ ovp_part,
    float* __restrict__ neg, double* __restrict__ pc_conf,
    double* __restrict__ pc_loc, int* __restrict__ pc_npos)
{
#pragma clang fp contract(off)
    const int b   = (int)blockIdx.x >> 6;
    const int p0  = ((int)blockIdx.x & 63) << 8;
    const int t   = (int)threadIdx.x;
    const int p   = p0 + t;
    const int idx = b * PP + p;

    __shared__ float  sls[256 * NCLS];
    __shared__ int    sforce[256];           // local prior -> forcing object
    __shared__ float4 sbox[NOBJ];
    __shared__ int    slab[NOBJ];
    __shared__ double sconf[4], sloc[4];
    __shared__ int    snp[4];

    // stage 256x21 scores tile via coalesced float4 loads
    {
        const float4* gsc = reinterpret_cast<const float4*>(
            scores + (size_t)(b * PP + p0) * NCLS);
        float4* dls = reinterpret_cast<float4*>(sls);
#pragma unroll
        for (int i = 0; i < 6; ++i) {
            int j = i * 256 + t;
            if (j < (256 * NCLS) / 4) dls[j] = gsc[j];
        }
    }
    sforce[t] = -1;
    if (t < NOBJ) {
        sbox[t] = reinterpret_cast<const float4*>(boxes)[b * NOBJ + t];
        slab[t] = labels[b * NOBJ + t];
    }
    __syncthreads();
    if (t < NOBJ) {
        unsigned long long k0 = bp_part[b * NOBJ + t];
#pragma unroll
        for (int cc = 1; cc < NCHK; ++cc) {
            unsigned long long kc = bp_part[(size_t)cc * BB * NOBJ + b * NOBJ + t];
            if (kc > k0) k0 = kc;
        }
        int spf = (int)(0xFFFFFFFFu - (unsigned)(k0 & 0xFFFFFFFFull));
        if (spf >= p0 && spf < p0 + 256)
            atomicMax(&sforce[spf - p0], t);   // max n = last-wins scatter
    }
    __syncthreads();

    // per-prior argmax: merge the 7 group partials (coalesced u32 loads)
    unsigned key = ovp_part[(size_t)b * PP + p];
#pragma unroll
    for (int g = 1; g < NGRP; ++g) {
        unsigned kg = ovp_part[((size_t)g * BB + b) * PP + p];
        if (kg > key) key = kg;
    }
    int   bestn = NOBJ - 1 - (int)(key & 63u);
    float v     = __uint_as_float((key >> 6) << 4);  // iou, low 4 bits cleared
    int fn = sforce[t];
    if (fn >= 0) { bestn = fn; v = 1.0f; }

    int lbl = slab[bestn];
    if (v < 0.5f) lbl = 0;
    const bool pos = (lbl != 0);

    float locl1 = 0.0f;
    if (pos) {
        float4 bx = sbox[bestn];
        float4 pc = reinterpret_cast<const float4*>(priors)[p];
        float cx = (bx.x + bx.z) / 2.0f;
        float cy = (bx.y + bx.w) / 2.0f;
        float w  = bx.z - bx.x, h = bx.w - bx.y;
        float gx = (cx - pc.x) / (pc.z / 10.0f);
        float gy = (cy - pc.y) / (pc.w / 10.0f);
        float gw = logf(w / pc.z) * 5.0f;
        float gh = logf(h / pc.w) * 5.0f;
        float4 pl = reinterpret_cast<const float4*>(locs)[idx];
        locl1 = fabsf(pl.x - gx) + fabsf(pl.y - gy) +
                fabsf(pl.z - gw) + fabsf(pl.w - gh);
    }

    // cross-entropy via log-softmax over 21 classes (from LDS)
    float x[NCLS];
    float m = -FLT_MAX;
#pragma unroll
    for (int c = 0; c < NCLS; ++c) { x[c] = sls[t * NCLS + c]; m = fmaxf(m, x[c]); }
    float tgt = sls[t * NCLS + lbl];
    float s = 0.0f;
#pragma unroll
    for (int c = 0; c < NCLS; ++c) s += expf(x[c] - m);
    float ce = (logf(s) + m) - tgt;

    neg[idx] = pos ? 0.0f : ce;

    // wave reductions -> per-block partials (NO global atomics)
    float cp = pos ? ce : 0.0f;
    unsigned long long bal = __ballot(pos);
    float s1 = cp, s2 = locl1;
    for (int o = 32; o > 0; o >>= 1) {
        s1 += __shfl_down(s1, o, 64);
        s2 += __shfl_down(s2, o, 64);
    }
    if ((t & 63) == 0) {
        int w = t >> 6;
        sconf[w] = (double)s1;
        sloc[w]  = (double)s2;
        snp[w]   = (int)__popcll(bal);
    }
    __syncthreads();
    if (t == 0) {
        pc_conf[blockIdx.x] = sconf[0] + sconf[1] + sconf[2] + sconf[3];
        pc_loc[blockIdx.x]  = sloc[0] + sloc[1] + sloc[2] + sloc[3];
        pc_npos[blockIdx.x] = snp[0] + snp[1] + snp[2] + snp[3];
    }
}

// exact top-K sum via 4x8-bit radix select; values register-resident,
// per-LANE histogram copies, wave-shuffle suffix scan (3 barriers/pass).
__global__ __launch_bounds__(1024) void k_topk(
    const float* __restrict__ neg, const int* __restrict__ pc_npos,
    double* __restrict__ hard)
{
    const int b    = (int)blockIdx.x;
    const int t    = (int)threadIdx.x;
    const int lane = t & 63;
    const int wid  = t >> 6;

    __shared__ unsigned hist[64 * 257];        // per-lane copies, padded
    __shared__ unsigned swsum[4];
    __shared__ unsigned s_bb, s_above;
    __shared__ float swave[16];
    __shared__ int s_np;

    if (t < 64) {
        int v = pc_npos[b * PBLK + t];
        for (int o = 32; o > 0; o >>= 1) v += __shfl_down(v, o, 64);
        if (t == 0) s_np = v;
    }

    float v[16];
    {
        const float4* g = reinterpret_cast<const float4*>(neg + (size_t)b * PP);
#pragma unroll
        for (int i = 0; i < 4; ++i) {
            float4 q = g[i * 1024 + t];
            v[i*4+0] = q.x; v[i*4+1] = q.y; v[i*4+2] = q.z; v[i*4+3] = q.w;
        }
    }
    __syncthreads();

    long long K = 3LL * (long long)s_np;
    if (K > PP) K = PP;
    unsigned remaining = (unsigned)K;
    unsigned prefix = 0, mask = 0;
    float mySum = 0.0f;

    for (int shift = 24; shift >= 0; shift -= 8) {
        for (int i = t; i < 64 * 257; i += 1024) hist[i] = 0;
        __syncthreads();
        unsigned* h = hist + lane * 257;
#pragma unroll
        for (int i = 0; i < 16; ++i) {
            unsigned u = __float_as_uint(v[i]);
            if ((u & mask) == prefix) atomicAdd(&h[(u >> shift) & 255u], 1u);
        }
        __syncthreads();
        // combine 64 copies -> cnt; per-wave shuffle suffix scan over 4 segs
        unsigned cnt = 0, suf = 0;
        if (t < 256) {
#pragma unroll
            for (int w = 0; w < 64; ++w) cnt += hist[w * 257 + t];
            unsigned vs = cnt;
#pragma unroll
            for (int off = 1; off < 64; off <<= 1) {
                unsigned o2 = __shfl_down(vs, off, 64);
                if (lane + off < 64) vs += o2;
            }
            if (lane == 0) swsum[wid] = vs;   // segment total (bins t..seg_end)
            suf = vs;
        }
        __syncthreads();
        if (t < 256) {
            for (int wseg = wid + 1; wseg < 4; ++wseg) suf += swsum[wseg];
            if (suf >= remaining && suf - cnt < remaining) {
                s_bb = (unsigned)t; s_above = suf - cnt;   // unique bin (cnt>0)
            }
        }
        __syncthreads();
        unsigned bb = s_bb;
#pragma unroll
        for (int i = 0; i < 16; ++i) {
            unsigned u = __float_as_uint(v[i]);
            if ((u & mask) == prefix && ((u >> shift) & 255u) > bb)
                mySum += v[i];
        }
        remaining -= s_above;
        prefix |= bb << shift;
        mask   |= 255u << shift;
        __syncthreads();
    }

    float s = mySum;
    for (int o = 32; o > 0; o >>= 1) s += __shfl_down(s, o, 64);
    if ((t & 63) == 0) swave[wid] = s;
    __syncthreads();
    if (t == 0) {
        float tot = 0.0f;
        for (int w = 0; w < 16; ++w) tot += swave[w];
        if (remaining) tot += (float)remaining * __uint_as_float(prefix);
        hard[b] = (double)tot;               // plain store, no atomics
    }
}

__global__ __launch_bounds__(256) void k_final(
    const double* __restrict__ pc_conf, const double* __restrict__ pc_loc,
    const int* __restrict__ pc_npos, const double* __restrict__ hard,
    float* __restrict__ out)
{
    const int t = (int)threadIdx.x;
    __shared__ double sa[4], sb[4], sh[4];
    __shared__ int sn[4];
    double a = 0.0, c = 0.0, h = 0.0; int np = 0;
    for (int i = t; i < NBLK; i += 256) {
        a += pc_conf[i]; c += pc_loc[i]; np += pc_npos[i];
    }
    if (t < BB) h = hard[t];
    for (int o = 32; o > 0; o >>= 1) {
        a += __shfl_down(a, o, 64);
        c += __shfl_down(c, o, 64);
        h += __shfl_down(h, o, 64);
        np += __shfl_down(np, o, 64);
    }
    if ((t & 63) == 0) { int w = t >> 6; sa[w]=a; sb[w]=c; sh[w]=h; sn[w]=np; }
    __syncthreads();
    if (t == 0) {
        double at = sa[0]+sa[1]+sa[2]+sa[3];
        double ct = sb[0]+sb[1]+sb[2]+sb[3];
        double ht = sh[0]+sh[1]+sh[2]+sh[3];
        double npt = (double)(sn[0]+sn[1]+sn[2]+sn[3]);
        out[0] = (float)((at + ht) / npt + ct / (npt * 4.0));
    }
}

extern "C" void kernel_launch(void* const* d_in, const int* in_sizes, int n_in,
                              void* d_out, int out_size, void* d_ws, size_t ws_size,
                              hipStream_t stream) {
    const float* locs   = (const float*)d_in[0];
    const float* scores = (const float*)d_in[1];
    const float* boxes  = (const float*)d_in[2];
    const int*   labels = (const int*)d_in[3];
    const float* priors = (const float*)d_in[4];

    char* ws = (char*)d_ws;
    unsigned long long* bp_part = (unsigned long long*)ws;
    double* pc_conf = (double*)(ws + 262144);
    double* pc_loc  = (double*)(ws + 278528);
    int*    pc_npos = (int*)(ws + 294912);
    double* hard    = (double*)(ws + 303104);
    unsigned* ovp_part = (unsigned*)(ws + 327680);
    float*  neg     = (float*)(ws + 33554432);
    float*  out     = (float*)d_out;

    hipLaunchKernelGGL(k_iou,   dim3(BB * NGRP * NCHK), dim3(256),  0, stream,
                       boxes, priors, bp_part, ovp_part);
    hipLaunchKernelGGL(k_main,  dim3(NBLK),             dim3(256),  0, stream,
                       locs, scores, boxes, labels, priors, bp_part, ovp_part,
                       neg, pc_conf, pc_loc, pc_npos);
    hipLaunchKernelGGL(k_topk,  dim3(BB),               dim3(1024), 0, stream,
                       neg, pc_npos, hard);
    hipLaunchKernelGGL(k_final, dim3(1),                dim3(256),  0, stream,
                       pc_conf, pc_loc, pc_npos, hard, out);
}